// Round 1
// baseline (65.260 us; speedup 1.0000x reference)
//
#include <hip/hip_runtime.h>

// MultiHuberLoss: input [65536, 1000] f32, target [65536] i32 -> scalar f32
//   m = (c == target[r]) ? x : -x
//   loss = (m >= -1) ? max(0, 1-m)^2 : -4*m
//   out = sum(loss) / 65536

constexpr int N_ROWS = 65536;
constexpr int N_COLS = 1000;
constexpr int F4_PER_ROW = N_COLS / 4;              // 250, rows are 16B-aligned (4000 B)
constexpr int TOTAL_F4 = N_ROWS * F4_PER_ROW;       // 16,384,000 — fits in int32

__global__ __launch_bounds__(256) void mhl_kernel(const float4* __restrict__ in,
                                                  const int* __restrict__ tgt,
                                                  float* __restrict__ out) {
    int idx = blockIdx.x * blockDim.x + threadIdx.x;
    int stride = gridDim.x * blockDim.x;
    float acc = 0.0f;

    for (int p = idx; p < TOTAL_F4; p += stride) {
        int row = p / F4_PER_ROW;                   // magic-multiply by compiler
        int c0 = (p - row * F4_PER_ROW) * 4;
        float4 v = in[p];
        int t = tgt[row];                           // L1/L2-resident (250 f4s share it)
        const float* vf = reinterpret_cast<const float*>(&v);
#pragma unroll
        for (int j = 0; j < 4; ++j) {
            float x = vf[j];
            float m = (c0 + j == t) ? x : -x;
            float h = fmaxf(0.0f, 1.0f - m);
            float l = (m >= -1.0f) ? h * h : -4.0f * m;
            acc += l;
        }
    }

    // wave64 butterfly reduce
#pragma unroll
    for (int off = 32; off > 0; off >>= 1)
        acc += __shfl_down(acc, off, 64);

    __shared__ float wsum[4];                       // 256 threads = 4 waves
    int wid = threadIdx.x >> 6;
    int lane = threadIdx.x & 63;
    if (lane == 0) wsum[wid] = acc;
    __syncthreads();

    if (threadIdx.x == 0) {
        float s = wsum[0] + wsum[1] + wsum[2] + wsum[3];
        atomicAdd(out, s * (1.0f / (float)N_ROWS));
    }
}

extern "C" void kernel_launch(void* const* d_in, const int* in_sizes, int n_in,
                              void* d_out, int out_size, void* d_ws, size_t ws_size,
                              hipStream_t stream) {
    const float4* in = (const float4*)d_in[0];
    const int* tgt = (const int*)d_in[1];
    float* out = (float*)d_out;

    // d_out is poisoned (0xAA) before timing and NOT re-poisoned between
    // replays — zero it ourselves every call (memset is graph-capture-safe).
    hipMemsetAsync(out, 0, sizeof(float), stream);

    // ~2048 blocks: 256 CUs x 8 blocks; each thread handles ~31 float4s.
    int block = 256;
    int grid = 2048;
    mhl_kernel<<<grid, block, 0, stream>>>(in, tgt, out);
}

// Round 2
// 56.129 us; speedup vs baseline: 1.1627x; 1.1627x over previous
//
#include <hip/hip_runtime.h>

// MultiHuberLoss: input [65536, 1000] f32, target [65536] i32 -> scalar f32
//   m = (c == target[r]) ? x : -x
//   loss = (m >= -1) ? max(0, 1-m)^2 : -4*m
//   out = sum(loss) / 65536

constexpr int N_ROWS = 65536;
constexpr int N_COLS = 1000;
constexpr int F4_PER_ROW = N_COLS / 4;                    // 250
constexpr int TOTAL_F4 = N_ROWS * F4_PER_ROW;             // 16,384,000

// grid chosen so stride is an exact multiple of a row:
// 2000*256 = 512,000 threads; 512,000 f4 = 2048 whole rows per stride;
// 16,384,000 / 512,000 = 32 iterations exactly (no tail, no bounds check).
constexpr int GRID = 2000;
constexpr int BLOCK = 256;
constexpr int STRIDE_F4 = GRID * BLOCK;                   // 512,000
constexpr int STRIDE_ROWS = STRIDE_F4 / F4_PER_ROW;       // 2048
constexpr int ITERS = TOTAL_F4 / STRIDE_F4;               // 32
constexpr int BATCH = 4;                                  // loads in flight per wave: 4 KB

__global__ __launch_bounds__(BLOCK) void mhl_kernel(const float4* __restrict__ in,
                                                    const int* __restrict__ tgt,
                                                    float* __restrict__ out) {
    int idx = blockIdx.x * BLOCK + threadIdx.x;

    int row = idx / F4_PER_ROW;                           // one divide, outside loop
    int c0 = (idx - row * F4_PER_ROW) * 4;                // loop-invariant column base
    int p = idx;

    float acc = 0.0f;

#pragma unroll 1
    for (int it = 0; it < ITERS / BATCH; ++it) {
        float4 v[BATCH];
        int t[BATCH];
        // issue all 8 loads back-to-back (independent addresses) before compute
#pragma unroll
        for (int j = 0; j < BATCH; ++j) {
            v[j] = in[p + j * STRIDE_F4];
            t[j] = tgt[row + j * STRIDE_ROWS];
        }
#pragma unroll
        for (int j = 0; j < BATCH; ++j) {
            const float* vf = reinterpret_cast<const float*>(&v[j]);
#pragma unroll
            for (int e = 0; e < 4; ++e) {
                float x = vf[e];
                float m = (c0 + e == t[j]) ? x : -x;
                float h = fmaxf(0.0f, 1.0f - m);
                float l = (m >= -1.0f) ? h * h : -4.0f * m;
                acc += l;
            }
        }
        p += BATCH * STRIDE_F4;
        row += BATCH * STRIDE_ROWS;
    }

    // wave64 butterfly reduce
#pragma unroll
    for (int off = 32; off > 0; off >>= 1)
        acc += __shfl_down(acc, off, 64);

    __shared__ float wsum[BLOCK / 64];
    int wid = threadIdx.x >> 6;
    int lane = threadIdx.x & 63;
    if (lane == 0) wsum[wid] = acc;
    __syncthreads();

    if (threadIdx.x == 0) {
        float s = wsum[0] + wsum[1] + wsum[2] + wsum[3];
        atomicAdd(out, s * (1.0f / (float)N_ROWS));
    }
}

extern "C" void kernel_launch(void* const* d_in, const int* in_sizes, int n_in,
                              void* d_out, int out_size, void* d_ws, size_t ws_size,
                              hipStream_t stream) {
    const float4* in = (const float4*)d_in[0];
    const int* tgt = (const int*)d_in[1];
    float* out = (float*)d_out;

    // d_out is poisoned (0xAA) before timing and NOT re-poisoned between
    // replays — zero it every call (memset is graph-capture-safe).
    hipMemsetAsync(out, 0, sizeof(float), stream);

    mhl_kernel<<<GRID, BLOCK, 0, stream>>>(in, tgt, out);
}